// Round 1
// baseline (106.412 us; speedup 1.0000x reference)
//
#include <hip/hip_runtime.h>

#define H 65536
#define CIN 64
#define COUT 128
#define NK 27
#define KTOT (NK*CIN)   // 1728
#define NB 64           // points per block in conv kernel

typedef unsigned short u16;
typedef unsigned int   u32;
typedef __attribute__((ext_vector_type(8))) short short8;   // 8 bf16 = 4 VGPRs (MFMA frag)
typedef __attribute__((ext_vector_type(4))) float f32x4;    // MFMA acc
typedef __attribute__((ext_vector_type(4))) unsigned int u32x4; // 16B vector

__device__ __forceinline__ u16 f2bf(float f) {
    u32 u = __float_as_uint(f);
    u = (u + 0x7FFFu + ((u >> 16) & 1u)) >> 16;   // RNE
    return (u16)u;
}

// ---------------------------------------------------------------------------
// Kernel 1a: x (64 x 65536 f32, c-major) -> x_t (65536 x 64 bf16, point-major)
// One thread per point row. Reads coalesced (lane = consecutive h for fixed c).
__global__ __launch_bounds__(256) void transpose_x(const float* __restrict__ x,
                                                   u16* __restrict__ xt) {
    const int h = blockIdx.x * 256 + threadIdx.x;
    u32 pk[32];
#pragma unroll
    for (int cp = 0; cp < 32; ++cp) {
        float f0 = x[(2 * cp)     * H + h];
        float f1 = x[(2 * cp + 1) * H + h];
        pk[cp] = (u32)f2bf(f0) | ((u32)f2bf(f1) << 16);
    }
    u32x4* dst = (u32x4*)(xt + (size_t)h * CIN);
#pragma unroll
    for (int i = 0; i < 8; ++i)
        dst[i] = *(u32x4*)&pk[i * 4];
}

// ---------------------------------------------------------------------------
// Kernel 1b: w (128 x 64 x 27 f32) -> wb[o][k*64+c] bf16
__global__ __launch_bounds__(256) void conv_w(const float* __restrict__ w,
                                              u16* __restrict__ wb) {
    const int tid = blockIdx.x * 256 + threadIdx.x;
    if (tid < COUT * KTOT) {
        const int o = tid / KTOT;
        const int rem = tid - o * KTOT;
        const int k = rem >> 6;
        const int c = rem & 63;
        wb[tid] = f2bf(w[o * KTOT + c * NK + k]);
    }
}

// ---------------------------------------------------------------------------
// Kernel 2: fused gather + GEMM.  out[o][n] = sum_k sum_c wb[o][k*64+c]*xt[neigh[n][k]][c]
// Block: 256 thr = 4 waves. Tile: all 128 o x 64 points. K-loop: 27 neighbors x 64 ch.
__global__ __launch_bounds__(256) void conv_mfma(const u16* __restrict__ xt,
                                                 const u16* __restrict__ wb,
                                                 const int* __restrict__ neigh,
                                                 float* __restrict__ out) {
    __shared__ u16 sB[NB * CIN];      // 8 KB, 16B-slot XOR-swizzled
    __shared__ int sIdx[NB * NK];     // 6912 B

    const int tid  = threadIdx.x;
    const int lane = tid & 63;
    const int w    = tid >> 6;        // wave 0..3
    const int n0   = blockIdx.x * NB;

    // stage the block's neighbor indices (contiguous global read)
    for (int i = tid; i < NB * NK; i += 256)
        sIdx[i] = neigh[n0 * NK + i];
    __syncthreads();

    f32x4 acc[2][4] = {};             // [o-frag][n-frag], each 16x16

    // staging assignment: lane covers point p = w*16 + it*8 + (lane>>3), slot s = lane&7
    const int pbase = w * 16 + (lane >> 3);
    const int s     = lane & 7;
    const int ro    = lane & 15;      // row/col within fragment
    const int kc    = (lane >> 4) * 8;

    // prologue: gather regs for k=0
    u32x4 rg[2];
#pragma unroll
    for (int it = 0; it < 2; ++it) {
        const int p = pbase + it * 8;
        const int j = sIdx[p * NK + 0];
        rg[it] = *(const u32x4*)(xt + (size_t)j * CIN + s * 8);
    }

    for (int k = 0; k < NK; ++k) {
        // A fragments for this k (L2-resident weight): issue early
        short8 afr[2][2];             // [c-half][o-frag]
#pragma unroll
        for (int hh = 0; hh < 2; ++hh)
#pragma unroll
            for (int f = 0; f < 2; ++f) {
                const int o = w * 32 + f * 16 + ro;
                afr[hh][f] = *(const short8*)(wb + (size_t)o * KTOT + k * CIN + hh * 32 + kc);
            }

        __syncthreads();              // previous iteration's LDS reads done
        // write staged gather regs -> LDS (XOR swizzle on 16B slots)
#pragma unroll
        for (int it = 0; it < 2; ++it) {
            const int p = pbase + it * 8;
            const int slot = s ^ (p & 7);
            *(u32x4*)(sB + p * CIN + slot * 8) = rg[it];
        }
        // prefetch gather for k+1 (overlaps with the MFMA phase)
        if (k + 1 < NK) {
#pragma unroll
            for (int it = 0; it < 2; ++it) {
                const int p = pbase + it * 8;
                const int j = sIdx[p * NK + (k + 1)];
                rg[it] = *(const u32x4*)(xt + (size_t)j * CIN + s * 8);
            }
        }
        __syncthreads();              // sB ready

        // MFMA: 2 K-steps of 32 channels
#pragma unroll
        for (int hh = 0; hh < 2; ++hh) {
            short8 bfr[4];
#pragma unroll
            for (int nf = 0; nf < 4; ++nf) {
                const int p = nf * 16 + ro;
                const int slin = hh * 4 + (lane >> 4);
                const int slot = slin ^ (p & 7);
                bfr[nf] = *(const short8*)(sB + p * CIN + slot * 8);
            }
#pragma unroll
            for (int f = 0; f < 2; ++f)
#pragma unroll
                for (int nf = 0; nf < 4; ++nf)
                    acc[f][nf] = __builtin_amdgcn_mfma_f32_16x16x32_bf16(
                        afr[hh][f], bfr[nf], acc[f][nf], 0, 0, 0);
        }
    }

    // epilogue: C/D layout (HW-verified): col = lane&15 (n), row = (lane>>4)*4 + r (o)
#pragma unroll
    for (int f = 0; f < 2; ++f)
#pragma unroll
        for (int nf = 0; nf < 4; ++nf)
#pragma unroll
            for (int r = 0; r < 4; ++r) {
                const int o = w * 32 + f * 16 + (lane >> 4) * 4 + r;
                const int n = n0 + nf * 16 + ro;
                out[(size_t)o * H + n] = acc[f][nf][r];
            }
}

// ---------------------------------------------------------------------------
// Kernel 3: per-channel sum/sumsq -> (scale, shift) for BN
__global__ __launch_bounds__(256) void bn_stats(const float* __restrict__ out,
                                                const float* __restrict__ gamma,
                                                const float* __restrict__ beta,
                                                float2* __restrict__ stats) {
    const int o = blockIdx.x;
    const float4* p = (const float4*)(out + (size_t)o * H);
    float s = 0.f, sq = 0.f;
    for (int i = threadIdx.x; i < H / 4; i += 256) {
        float4 v = p[i];
        s  += v.x + v.y + v.z + v.w;
        sq += v.x * v.x + v.y * v.y + v.z * v.z + v.w * v.w;
    }
    __shared__ float sh[512];
    sh[threadIdx.x] = s;
    sh[256 + threadIdx.x] = sq;
    __syncthreads();
    for (int st = 128; st > 0; st >>= 1) {
        if (threadIdx.x < st) {
            sh[threadIdx.x]       += sh[threadIdx.x + st];
            sh[256 + threadIdx.x] += sh[256 + threadIdx.x + st];
        }
        __syncthreads();
    }
    if (threadIdx.x == 0) {
        const float mean = sh[0] / (float)H;
        const float var  = sh[256] / (float)H - mean * mean;
        const float rstd = rsqrtf(var + 1e-5f);
        const float a = gamma[o] * rstd;
        stats[o] = make_float2(a, beta[o] - mean * a);
    }
}

// ---------------------------------------------------------------------------
// Kernel 4: in-place BN + ReLU, float4 vectorized
__global__ __launch_bounds__(256) void bn_relu(float* __restrict__ out,
                                               const float2* __restrict__ stats) {
    const int idx = blockIdx.x * 256 + threadIdx.x;  // float4 index
    const int o = idx >> 14;                          // 16384 float4 per channel
    const float2 ab = stats[o];
    float4* p = (float4*)out;
    float4 v = p[idx];
    v.x = fmaxf(fmaf(v.x, ab.x, ab.y), 0.f);
    v.y = fmaxf(fmaf(v.y, ab.x, ab.y), 0.f);
    v.z = fmaxf(fmaf(v.z, ab.x, ab.y), 0.f);
    v.w = fmaxf(fmaf(v.w, ab.x, ab.y), 0.f);
    p[idx] = v;
}

// ---------------------------------------------------------------------------
extern "C" void kernel_launch(void* const* d_in, const int* in_sizes, int n_in,
                              void* d_out, int out_size, void* d_ws, size_t ws_size,
                              hipStream_t stream) {
    const float* x     = (const float*)d_in[0];  // (1,64,65536,1)
    const int*   neigh = (const int*)d_in[1];    // (65536,27)
    const float* w     = (const float*)d_in[2];  // (128,64,27)
    const float* gamma = (const float*)d_in[3];
    const float* beta  = (const float*)d_in[4];
    float* out = (float*)d_out;                  // (1,128,65536,1)

    char* ws = (char*)d_ws;
    u16* xt = (u16*)ws;                               // 65536*64*2 = 8388608 B
    u16* wb = (u16*)(ws + 8388608);                   // 128*1728*2 = 442368 B
    float2* stats = (float2*)(ws + 8388608 + 442368); // 128*8 B

    transpose_x<<<H / 256, 256, 0, stream>>>(x, xt);
    conv_w<<<(COUT * KTOT + 255) / 256, 256, 0, stream>>>(w, wb);
    conv_mfma<<<H / NB, 256, 0, stream>>>(xt, wb, neigh, out);
    bn_stats<<<COUT, 256, 0, stream>>>(out, gamma, beta, stats);
    bn_relu<<<(COUT * H / 4) / 256, 256, 0, stream>>>(out, stats);
}